// Round 5
// baseline (588.965 us; speedup 1.0000x reference)
//
#include <hip/hip_runtime.h>
#include <stdint.h>

#define B_     128
#define T_     64
#define HW_    2048
#define N_     131072
#define NB_    16384      /* N_/8 bytes of src bitmask per row */
#define BINS1  8192
#define SHIFT1 19
#define MARGIN 512u       /* band margin in key-ulps (>= 3x fast-log drift) */
#define RMARG  6000       /* sampling rank margin (~12 sigma) */
#define SEG    4          /* sampled-hist partials per row */
#define NB2    9216       /* resolveE sub-bins (dynamic width) */
#define WCAP   2048
#define SGRID  (B_ * SEG) /* 512 blocks */
#define FULLG  (B_ * 64)  /* maskD: 64 t-slots/row, 2048 elems per block */

// ---------- helpers ----------

__device__ __forceinline__ uint32_t fkey(float p) {
  uint32_t u = __float_as_uint(p);
  return u ^ ((u & 0x80000000u) ? 0xFFFFFFFFu : 0x80000000u);
}

// fast natural log: hardware v_log_f32 (log2) * ln2; deterministic.
__device__ __forceinline__ float fastln(float x) {
  #pragma clang fp contract(off)
  float l2 = __log2f(x);
  return l2 * 0.6931471805599453f;
}

// exact: correctly-rounded f32 natural log via double (matches numpy f32 log — verified R2-R4)
__device__ __forceinline__ float exactln(float x) {
  return (float)log((double)x);
}

// ---------- LUT: per (b,t) constants, exact f32 semantics ----------
__global__ void lut_kernel(const float* __restrict__ Uts, const float* __restrict__ Utt,
                           float* c1src, float* c1tgt, float* cpref) {
  #pragma clang fp contract(off)
  int b = blockIdx.x, t = threadIdx.x;
  c1src[b * T_ + t] = exactln(Uts[b * T_ + t]) * 0.5f;
  c1tgt[b * T_ + t] = exactln(Utt[b * T_ + t]) * 0.5f;
  if (b == 0) {
    const double st = (0.001 - 1.0) / 63.0;   // numpy linspace step (f64)
    double a = (double)t * st;
    double y = a + 1.0;
    if (t == 63) y = 0.001;                   // numpy endpoint fixup
    float L = (float)y;
    float ex = (float)(1.0 / 3.0);
    float pf = (float)pow((double)L, (double)ex);
    if (pf < 1e-9f) pf = 1e-9f;
    cpref[t] = exactln(pf);
    if (t == 0) cpref[64] = exactln(1e-9f);
  }
}

// ---------- S: sampled histogram (1/8 of elements), non-atomic partial flush ----------
template <bool TGT>
__global__ __launch_bounds__(256) void sampleHist(const float* __restrict__ U0,
                                                  const float* __restrict__ c1lut,
                                                  const float* __restrict__ cpref,
                                                  const uint8_t* __restrict__ bits,
                                                  uint32_t* __restrict__ hist1) {
  #pragma clang fp contract(off)
  __shared__ uint32_t lh[BINS1];
  for (int i = threadIdx.x; i < BINS1; i += 256) lh[i] = 0;
  __syncthreads();
  int row = blockIdx.x >> 2, seg = blockIdx.x & 3;
  const float* rowp = U0 + (size_t)row * N_;
  float lc9 = cpref[64];
  // quarter-row slice: 32768 elems = 4096 groups of 8; sample every 8th group (512)
  #pragma unroll
  for (int k = 0; k < 2; k++) {
    int s = threadIdx.x + k * 256;           // sampled-group index [0,512)
    int base = seg * 32768 + s * 64;         // element index within row
    int t = base >> 11;
    const float4* p = (const float4*)(rowp + base);
    float4 va = p[0], vb = p[1];
    float u[8] = {va.x, va.y, va.z, va.w, vb.x, vb.y, vb.z, vb.w};
    float c1 = c1lut[row * T_ + t];
    float c2s = cpref[t];
    uint8_t byte = TGT ? bits[(size_t)row * NB_ + (base >> 3)] : (uint8_t)0;
    #pragma unroll
    for (int j = 0; j < 8; j++) {
      float c2 = TGT ? ((((byte >> j) & 1) != 0) ? lc9 : 0.0f) : c2s;
      float P = (fastln(u[j]) + c1) + c2;
      atomicAdd(&lh[fkey(P) >> SHIFT1], 1u);
    }
  }
  __syncthreads();
  uint32_t* gh = hist1 + ((size_t)(row * SEG + seg)) * BINS1;
  for (int i = threadIdx.x * 4; i < BINS1; i += 1024) {
    uint4 v = *(uint4*)&lh[i];
    *(uint4*)&gh[i] = v;
  }
}

// ---------- pick band [kLo,kHi] from sampled hist via rank margins ----------
__global__ __launch_bounds__(256) void pickband(const uint32_t* __restrict__ hist1,
                                                const int* __restrict__ pK,
                                                uint32_t* kLoA, uint32_t* kHiA,
                                                uint32_t* bandcnt, uint32_t* cntabove) {
  __shared__ uint32_t sum[BINS1];
  __shared__ uint32_t sh[256];
  int row = blockIdx.x;
  const uint32_t* h = hist1 + (size_t)row * SEG * BINS1;
  for (int i = threadIdx.x; i < BINS1; i += 256) {
    uint32_t s = 0;
    #pragma unroll
    for (int g = 0; g < SEG; g++) s += h[g * BINS1 + i];
    sum[i] = s;
  }
  __syncthreads();
  const int CH = BINS1 / 256;
  {
    uint32_t s = 0;
    int c0 = threadIdx.x * CH;
    for (int i = 0; i < CH; i++) s += sum[c0 + i];
    sh[threadIdx.x] = s;
  }
  __syncthreads();
  if (threadIdx.x == 0) {
    long long K = (long long)*pK;
    long long Thi = K - RMARG;    // trigger: 8S >  Thi  -> kHi = top of bin
    long long Tlo = K + RMARG;    // trigger: 8S >= Tlo  -> kLo = bottom of bin
    uint32_t kHi = 0xFFFFFFFFu, kLo = 0u;
    // scan 1: kHi
    {
      long long S = 0; bool done = false;
      for (int c = 255; c >= 0 && !done; c--) {
        if (8LL * (S + sh[c]) > Thi) {
          long long s2 = S;
          for (int b = c * CH + CH - 1; b >= c * CH; b--) {
            s2 += sum[b];
            if (8LL * s2 > Thi) { kHi = (((uint32_t)b + 1u) << SHIFT1) - 1u; done = true; break; }
          }
        }
        S += sh[c];
      }
      if (!done) kHi = 0xFFFFFFFFu;
    }
    // scan 2: kLo
    {
      long long S = 0; bool done = false;
      for (int c = 255; c >= 0 && !done; c--) {
        if (8LL * (S + sh[c]) >= Tlo) {
          long long s2 = S;
          for (int b = c * CH + CH - 1; b >= c * CH; b--) {
            s2 += sum[b];
            if (8LL * s2 >= Tlo) { kLo = ((uint32_t)b) << SHIFT1; done = true; break; }
          }
        }
        S += sh[c];
      }
      if (!done) kLo = 0u;
    }
    kLoA[row] = kLo;
    kHiA[row] = kHi;
    bandcnt[row] = 0;
    cntabove[row] = 0;
  }
}

// ---------- D: write mask (int32 0/1), gather band (idx,fastkey), exact count-above ----------
template <bool TGT>
__global__ __launch_bounds__(256) void maskD(const float* __restrict__ U0,
                                             const float* __restrict__ c1lut,
                                             const float* __restrict__ cpref,
                                             const uint8_t* __restrict__ bits_in,
                                             const uint32_t* __restrict__ kLoA,
                                             const uint32_t* __restrict__ kHiA,
                                             int* __restrict__ out,
                                             uint8_t* __restrict__ bits_out,
                                             uint32_t* __restrict__ bandcnt,
                                             uint32_t* __restrict__ cntabove,
                                             uint2* __restrict__ bandpair,
                                             uint32_t cap) {
  #pragma clang fp contract(off)
  __shared__ uint32_t lbase, labove, gbase;
  if (threadIdx.x == 0) { lbase = 0; labove = 0; }
  __syncthreads();
  int row = blockIdx.x >> 6, slot = blockIdx.x & 63;
  int n0 = slot * HW_ + threadIdx.x * 8;
  uint32_t kLo = kLoA[row], kHi = kHiA[row];
  uint32_t blo = (kLo >= MARGIN) ? kLo - MARGIN : 0u;
  uint32_t bhi2 = kHi + MARGIN;
  uint32_t bhi = (bhi2 < kHi) ? 0xFFFFFFFFu : bhi2;   // saturate
  const float4* p = (const float4*)(U0 + (size_t)row * N_ + n0);
  float4 va = p[0], vb = p[1];
  float u[8] = {va.x, va.y, va.z, va.w, vb.x, vb.y, vb.z, vb.w};
  float c1 = c1lut[row * T_ + slot];
  float c2s = cpref[slot];
  float lc9 = cpref[64];
  uint8_t byte = TGT ? bits_in[(size_t)row * NB_ + (n0 >> 3)] : (uint8_t)0;
  int ov[8];
  uint32_t kk[8];
  uint32_t bandmask = 0, abovemask = 0;
  #pragma unroll
  for (int j = 0; j < 8; j++) {
    float c2 = TGT ? ((((byte >> j) & 1) != 0) ? lc9 : 0.0f) : c2s;
    float P = (fastln(u[j]) + c1) + c2;
    uint32_t k = fkey(P);
    kk[j] = k;
    if (k > bhi) { ov[j] = 1; abovemask |= (1u << j); }
    else { ov[j] = 0; if (k >= blo) bandmask |= (1u << j); }
  }
  int4 o0 = {ov[0], ov[1], ov[2], ov[3]};
  int4 o1 = {ov[4], ov[5], ov[6], ov[7]};
  int4* q = (int4*)(out + (size_t)row * N_ + n0);
  q[0] = o0; q[1] = o1;
  if (!TGT) bits_out[(size_t)row * NB_ + (n0 >> 3)] = (uint8_t)abovemask;
  int bp = __popc(bandmask), ap = __popc(abovemask);
  uint32_t mybase = 0;
  if (bp) mybase = atomicAdd(&lbase, (uint32_t)bp);
  if (ap) atomicAdd(&labove, (uint32_t)ap);
  __syncthreads();
  if (threadIdx.x == 0) {
    gbase = lbase ? atomicAdd(&bandcnt[row], lbase) : 0u;
    if (labove) atomicAdd(&cntabove[row], labove);
  }
  __syncthreads();
  if (bp) {
    uint32_t base = gbase + mybase;
    uint2* br = bandpair + (size_t)row * cap;
    #pragma unroll
    for (int j = 0; j < 8; j++)
      if ((bandmask >> j) & 1u) {
        uint32_t pos = base + (uint32_t)__popc(bandmask & ((1u << j) - 1u));
        if (pos < cap) { uint2 e; e.x = (uint32_t)(n0 + j); e.y = kk[j]; br[pos] = e; }
      }
  }
}

// ---------- E: streaming fast-key refine (dynamic sub-bin width) + tiny exact resolve ----------
template <bool TGT>
__global__ __launch_bounds__(1024) void resolveE(const float* __restrict__ U0,
                                                 const float* __restrict__ c1lut,
                                                 const float* __restrict__ cpref,
                                                 const uint8_t* __restrict__ bits_in,
                                                 const int* __restrict__ pK,
                                                 const uint32_t* __restrict__ kLoA,
                                                 const uint32_t* __restrict__ kHiA,
                                                 const uint32_t* __restrict__ bandcnt,
                                                 const uint32_t* __restrict__ cntabove,
                                                 const uint2* __restrict__ bandpair,
                                                 int* __restrict__ out,
                                                 uint8_t* __restrict__ bits_out,
                                                 uint32_t cap) {
  #pragma clang fp contract(off)
  __shared__ uint32_t subh[NB2];
  __shared__ uint32_t sh2[1024];
  __shared__ uint32_t wk[WCAP];
  __shared__ uint32_t wi[WCAP];
  __shared__ uint32_t s_sbin, s_A, s_nw;
  int row = blockIdx.x;
  for (int i = threadIdx.x; i < NB2; i += 1024) subh[i] = 0;
  if (threadIdx.x == 0) s_nw = 0;
  __syncthreads();
  uint32_t cnt = bandcnt[row]; if (cnt > cap) cnt = cap;
  uint32_t K = (uint32_t)*pK;
  uint32_t R = K - cntabove[row];           // band elements to select; >=1 by construction
  uint32_t kLo = kLoA[row], kHi = kHiA[row];
  uint32_t blo = (kLo >= MARGIN) ? kLo - MARGIN : 0u;
  uint32_t bhi2 = kHi + MARGIN;
  uint32_t bhi = (bhi2 < kHi) ? 0xFFFFFFFFu : bhi2;
  uint32_t range = bhi - blo;
  int wb = 6;                               // sub-bin width = 2^wb ulps, >= 64
  while ((range >> wb) + 2u > (uint32_t)NB2) wb++;
  int NW = (int)(2048u >> wb); if (NW < 2) NW = 2;   // window half-width in sub-bins (>=2048 ulps)
  const uint2* bp = bandpair + (size_t)row * cap;

  // pass 1: fast-key sub-histogram, sequential stream
  for (uint32_t i = threadIdx.x; i < cnt; i += 1024) {
    uint32_t bin = (bp[i].y - blo) >> wb;
    if (bin >= (uint32_t)NB2) bin = NB2 - 1;
    atomicAdd(&subh[bin], 1u);
  }
  __syncthreads();
  const int CH2 = NB2 / 1024;   // 9
  {
    uint32_t s = 0;
    int c0 = threadIdx.x * CH2;
    #pragma unroll
    for (int i = 0; i < CH2; i++) s += subh[c0 + i];
    sh2[threadIdx.x] = s;
  }
  __syncthreads();
  if (threadIdx.x == 0) {
    uint32_t cum = 0, chi = 0; int sbin = 0;
    for (int c = 1023; c >= 0; c--) {
      if (cum + sh2[c] >= R) {
        uint32_t cc = cum;
        for (int b0 = c * CH2 + CH2 - 1; b0 >= c * CH2; b0--) {
          uint32_t hv = subh[b0];
          if (cc + hv >= R) { sbin = b0; chi = cc; break; }
          cc += hv;
        }
        break;
      }
      cum += sh2[c];
    }
    // chi = count(bins > sbin). A = count(bins > sbin+NW)
    uint32_t sm = 0;
    for (int k2 = 1; k2 <= NW; k2++) {
      int b2 = sbin + k2;
      if (b2 < NB2) sm += subh[b2];
    }
    s_sbin = (uint32_t)sbin;
    s_A = chi - sm;
  }
  __syncthreads();
  int sbin = (int)s_sbin;
  uint32_t A = s_A;
  uint32_t R2 = R - A;                      // to select from W window; >=1
  int* orow = out + (size_t)row * N_;

  // pass 2: classify band; definite-selects written, W collected
  for (uint32_t i = threadIdx.x; i < cnt; i += 1024) {
    uint2 e = bp[i];
    uint32_t bin = (e.y - blo) >> wb;
    if (bin >= (uint32_t)NB2) bin = NB2 - 1;
    if ((int)bin > sbin + NW) {
      orow[e.x] = 1;
      if (!TGT) atomicOr((uint32_t*)(bits_out + (size_t)row * NB_) + (e.x >> 5), 1u << (e.x & 31));
    } else if ((int)bin >= sbin - NW) {
      uint32_t ppos = atomicAdd(&s_nw, 1u);
      if (ppos < WCAP) wi[ppos] = e.x;
    }
  }
  __syncthreads();
  uint32_t nw = s_nw; if (nw > WCAP) nw = WCAP;
  // pass 3a: exact keys for W
  const uint8_t* rb = bits_in + (size_t)row * NB_;
  const float* rowp = U0 + (size_t)row * N_;
  float lc9 = cpref[64];
  for (uint32_t i = threadIdx.x; i < nw; i += 1024) {
    uint32_t idx = wi[i];
    uint32_t t = idx >> 11;
    float c2 = TGT ? ((((rb[idx >> 3] >> (idx & 7)) & 1) != 0) ? lc9 : 0.0f) : cpref[t];
    float P = (exactln(rowp[idx]) + c1lut[row * T_ + t]) + c2;
    wk[i] = fkey(P);
  }
  __syncthreads();
  // pass 3b: stable pairwise rank in W, select top R2
  for (uint32_t i = threadIdx.x; i < nw; i += 1024) {
    uint32_t k = wk[i], id = wi[i], r = 0;
    for (uint32_t j = 0; j < nw; j++) {
      uint32_t kj = wk[j];
      r += (uint32_t)((kj > k) || (kj == k && wi[j] < id));
    }
    if (r < R2) {
      orow[id] = 1;
      if (!TGT) atomicOr((uint32_t*)(bits_out + (size_t)row * NB_) + (id >> 5), 1u << (id & 31));
    }
  }
}

// ---------- launch ----------
extern "C" void kernel_launch(void* const* d_in, const int* in_sizes, int n_in,
                              void* d_out, int out_size, void* d_ws, size_t ws_size,
                              hipStream_t stream) {
  const float* U0s = (const float*)d_in[0];
  const float* Uts = (const float*)d_in[1];
  const float* U0t = (const float*)d_in[2];
  const float* Utt = (const float*)d_in[3];
  const int* Ks = (const int*)d_in[4];
  const int* Kt = (const int*)d_in[5];
  int* out = (int*)d_out;
  char* ws = (char*)d_ws;

  // ws layout: bandpair (cap*128*8 B; cap up to full row) | bits 2 MiB | small LUTs.
  // hist1 (SEG*128*8192*4 = 16 MiB) aliases bandpair head: hist is consumed by
  // pickband before maskD writes bandpair.
  const size_t fixed = 2097152 + 131072;   // bits + small area
  size_t avail = (ws_size > fixed) ? (ws_size - fixed) : 0;
  uint32_t cap = (uint32_t)(avail / ((size_t)B_ * 8));
  if (cap > (uint32_t)N_) cap = N_;
  size_t bandBytes = (size_t)cap * B_ * 8;
  if (bandBytes < 16777216) bandBytes = 16777216;  // ensure hist fits the alias region

  uint2*    bandpair = (uint2*)ws;
  uint32_t* hist1    = (uint32_t*)ws;
  uint8_t*  bits     = (uint8_t*)(ws + bandBytes);
  char*     sm       = ws + bandBytes + 2097152;
  uint32_t* bandcnt  = (uint32_t*)(sm + 0);
  uint32_t* cntabv   = (uint32_t*)(sm + 512);
  uint32_t* kLoA     = (uint32_t*)(sm + 1024);
  uint32_t* kHiA     = (uint32_t*)(sm + 1536);
  float*    c1src    = (float*)(sm + 2048);
  float*    c1tgt    = (float*)(sm + 2048 + 32768);
  float*    cpref    = (float*)(sm + 2048 + 65536);

  lut_kernel<<<B_, T_, 0, stream>>>(Uts, Utt, c1src, c1tgt, cpref);

  // ---- SRC mask -> out[0 .. B*N) ----
  sampleHist<false><<<SGRID, 256, 0, stream>>>(U0s, c1src, cpref, nullptr, hist1);
  pickband<<<B_, 256, 0, stream>>>(hist1, Ks, kLoA, kHiA, bandcnt, cntabv);
  maskD<false><<<FULLG, 256, 0, stream>>>(U0s, c1src, cpref, nullptr, kLoA, kHiA,
                                          out, bits, bandcnt, cntabv, bandpair, cap);
  resolveE<false><<<B_, 1024, 0, stream>>>(U0s, c1src, cpref, nullptr, Ks, kLoA, kHiA,
                                           bandcnt, cntabv, bandpair, out, bits, cap);

  // ---- TGT mask (conditioned on src bits) -> out[B*N .. 2*B*N) ----
  int* out2 = out + (size_t)B_ * N_;
  sampleHist<true><<<SGRID, 256, 0, stream>>>(U0t, c1tgt, cpref, bits, hist1);
  pickband<<<B_, 256, 0, stream>>>(hist1, Kt, kLoA, kHiA, bandcnt, cntabv);
  maskD<true><<<FULLG, 256, 0, stream>>>(U0t, c1tgt, cpref, bits, kLoA, kHiA,
                                         out2, nullptr, bandcnt, cntabv, bandpair, cap);
  resolveE<true><<<B_, 1024, 0, stream>>>(U0t, c1tgt, cpref, bits, Kt, kLoA, kHiA,
                                          bandcnt, cntabv, bandpair, out2, nullptr, cap);
}

// Round 6
// 399.588 us; speedup vs baseline: 1.4739x; 1.4739x over previous
//
#include <hip/hip_runtime.h>
#include <stdint.h>

#define B_     128
#define T_     64
#define HW_    2048
#define N_     131072
#define NB_    16384      /* N_/8 bytes of src bitmask per row */
#define MSAMP  16384      /* samples per row (1/8) */
#define CBINS  8192       /* coarse bins (13-bit) */
#define CSH    19
#define FBINS  8192       /* fine zoom bins */
#define RMARG  3072       /* rank margin ~6 sigma (sigma ~= 512) */
#define MARGIN 512u       /* key-ulp margin >= 60x fast-log drift */
#define NB2    9216       /* resolveE sub-bins = 1024*9 */
#define WCAP   2048
#define CAP    32768      /* bandpair capacity per row */
#define FULLG  (B_ * 64)

// ---------- helpers ----------

__device__ __forceinline__ uint32_t fkey(float p) {
  uint32_t u = __float_as_uint(p);
  return u ^ ((u & 0x80000000u) ? 0xFFFFFFFFu : 0x80000000u);
}

__device__ __forceinline__ float fastln(float x) {
  #pragma clang fp contract(off)
  float l2 = __log2f(x);
  return l2 * 0.6931471805599453f;
}

__device__ __forceinline__ float exactln(float x) {
  return (float)log((double)x);
}

// ---------- LUT ----------
__global__ void lut_kernel(const float* __restrict__ Uts, const float* __restrict__ Utt,
                           float* c1src, float* c1tgt, float* cpref) {
  #pragma clang fp contract(off)
  int b = blockIdx.x, t = threadIdx.x;
  c1src[b * T_ + t] = exactln(Uts[b * T_ + t]) * 0.5f;
  c1tgt[b * T_ + t] = exactln(Utt[b * T_ + t]) * 0.5f;
  if (b == 0) {
    const double st = (0.001 - 1.0) / 63.0;
    double a = (double)t * st;
    double y = a + 1.0;
    if (t == 63) y = 0.001;
    float L = (float)y;
    float ex = (float)(1.0 / 3.0);
    float pf = (float)pow((double)L, (double)ex);
    if (pf < 1e-9f) pf = 1e-9f;
    cpref[t] = exactln(pf);
    if (t == 0) cpref[64] = exactln(1e-9f);
  }
}

// ---------- sampleBand: per-row sampled 2-level refine -> tight [kLo,kHi] ----------
template <bool TGT>
__global__ __launch_bounds__(1024) void sampleBand(const float* __restrict__ U0,
                                                   const float* __restrict__ c1lut,
                                                   const float* __restrict__ cpref,
                                                   const uint8_t* __restrict__ bits,
                                                   const int* __restrict__ pK,
                                                   uint32_t* kLoA, uint32_t* kHiA,
                                                   uint32_t* bandcnt, uint32_t* cntabove) {
  #pragma clang fp contract(off)
  __shared__ uint32_t h[CBINS];     // 32 KB (reused coarse then fine)
  __shared__ uint32_t ss[1024];     // 4 KB
  __shared__ int s_bin[2];
  __shared__ uint32_t s_abv[2];
  int row = blockIdx.x, tid = threadIdx.x;
  for (int i = tid; i < CBINS; i += 1024) h[i] = 0;
  __syncthreads();
  const float* rowp = U0 + (size_t)row * N_;
  float lc9 = cpref[64];

  // pass 1: sampled keys -> coarse hist (sample = first 8 of every 64 elems)
  #pragma unroll
  for (int g = 0; g < 2; g++) {
    int grp = tid + g * 1024;
    int base = grp * 64;
    int t = base >> 11;
    const float4* p = (const float4*)(rowp + base);
    float4 va = p[0], vb = p[1];
    float u[8] = {va.x, va.y, va.z, va.w, vb.x, vb.y, vb.z, vb.w};
    float c1 = c1lut[row * T_ + t];
    float c2s = cpref[t];
    uint8_t byte = TGT ? bits[(size_t)row * NB_ + (base >> 3)] : (uint8_t)0;
    #pragma unroll
    for (int j = 0; j < 8; j++) {
      float c2 = TGT ? ((((byte >> j) & 1) != 0) ? lc9 : 0.0f) : c2s;
      uint32_t k = fkey((fastln(u[j]) + c1) + c2);
      atomicAdd(&h[k >> CSH], 1u);
    }
  }
  __syncthreads();

  int K = *pK;
  long long rHiL = ((long long)K - RMARG) / 8;
  long long rLoL = ((long long)K + RMARG + 7) / 8;
  bool hiV = rHiL >= 1;
  bool loV = rLoL <= (long long)MSAMP;
  uint32_t rHi = hiV ? (uint32_t)rHiL : 1u;
  uint32_t rLo = loV ? (uint32_t)rLoL : (uint32_t)MSAMP;

  // coarse suffix scan over 1024 chunks of 8
  {
    uint32_t s = 0; int c0 = tid * 8;
    #pragma unroll
    for (int i = 0; i < 8; i++) s += h[c0 + i];
    ss[tid] = s;
  }
  __syncthreads();
  for (int d = 1; d < 1024; d <<= 1) {
    uint32_t v = ss[tid] + ((tid + d < 1024) ? ss[tid + d] : 0u);
    __syncthreads();
    ss[tid] = v;
    __syncthreads();
  }
  // parallel bin find for rHi (q=0) and rLo (q=1)
  #pragma unroll
  for (int q = 0; q < 2; q++) {
    uint32_t r = q ? rLo : rHi;
    bool hit = (ss[tid] >= r) && (tid == 1023 || ss[tid + 1] < r);
    if (hit) {
      uint32_t run = (tid == 1023) ? 0u : ss[tid + 1];
      int b = tid * 8 + 7;
      for (; b > tid * 8; b--) {
        uint32_t nb = run + h[b];
        if (nb >= r) break;
        run = nb;
      }
      if (run + h[b] < r) { /* unreachable */ }
      s_bin[q] = b;
      s_abv[q] = run;      // samples strictly above bin b
    }
  }
  __syncthreads();
  int bHi = hiV ? s_bin[0] : (CBINS - 1);
  uint32_t abvR = hiV ? s_abv[0] : 0u;
  int bLo = loV ? s_bin[1] : 0;
  if (bLo > bHi) bLo = bHi;
  uint32_t lo0 = (uint32_t)bLo << CSH;
  unsigned long long range = ((unsigned long long)(bHi - bLo + 1)) << CSH;
  int wb = 6;
  while ((range >> wb) > (unsigned long long)FBINS) wb++;
  __syncthreads();
  // fine hist (recompute sample keys; data is L2-hot)
  for (int i = tid; i < FBINS; i += 1024) h[i] = 0;
  __syncthreads();
  #pragma unroll
  for (int g = 0; g < 2; g++) {
    int grp = tid + g * 1024;
    int base = grp * 64;
    int t = base >> 11;
    const float4* p = (const float4*)(rowp + base);
    float4 va = p[0], vb = p[1];
    float u[8] = {va.x, va.y, va.z, va.w, vb.x, vb.y, vb.z, vb.w};
    float c1 = c1lut[row * T_ + t];
    float c2s = cpref[t];
    uint8_t byte = TGT ? bits[(size_t)row * NB_ + (base >> 3)] : (uint8_t)0;
    #pragma unroll
    for (int j = 0; j < 8; j++) {
      float c2 = TGT ? ((((byte >> j) & 1) != 0) ? lc9 : 0.0f) : c2s;
      uint32_t k = fkey((fastln(u[j]) + c1) + c2);
      unsigned long long off = (unsigned long long)k - lo0;
      if (k >= lo0 && off < range) atomicAdd(&h[(uint32_t)(off >> wb)], 1u);
    }
  }
  __syncthreads();
  // fine suffix scan
  {
    uint32_t s = 0; int c0 = tid * 8;
    #pragma unroll
    for (int i = 0; i < 8; i++) s += h[c0 + i];
    ss[tid] = s;
  }
  __syncthreads();
  for (int d = 1; d < 1024; d <<= 1) {
    uint32_t v = ss[tid] + ((tid + d < 1024) ? ss[tid + d] : 0u);
    __syncthreads();
    ss[tid] = v;
    __syncthreads();
  }
  uint32_t rHi2 = rHi - abvR;
  uint32_t rLo2 = rLo - abvR;
  #pragma unroll
  for (int q = 0; q < 2; q++) {
    if (q == 0 && !hiV) continue;
    if (q == 1 && !loV) continue;
    uint32_t r = q ? rLo2 : rHi2;
    bool hit = (ss[tid] >= r) && (tid == 1023 || ss[tid + 1] < r);
    if (hit) {
      uint32_t run = (tid == 1023) ? 0u : ss[tid + 1];
      int b = tid * 8 + 7;
      for (; b > tid * 8; b--) {
        uint32_t nb = run + h[b];
        if (nb >= r) break;
        run = nb;
      }
      s_bin[q] = b;
    }
  }
  __syncthreads();
  if (tid == 0) {
    uint32_t kHi = hiV ? (uint32_t)((unsigned long long)lo0 +
                      (((unsigned long long)(s_bin[0] + 1)) << wb) - 1ull) : 0xFFFFFFFFu;
    uint32_t kLo = loV ? (lo0 + ((uint32_t)s_bin[1] << wb)) : 0u;
    kHiA[row] = kHi;
    kLoA[row] = kLo;
    bandcnt[row] = 0;
    cntabove[row] = 0;
  }
}

// ---------- D: write mask (int32 0/1), gather band (idx,fastkey), exact count-above ----------
template <bool TGT>
__global__ __launch_bounds__(256) void maskD(const float* __restrict__ U0,
                                             const float* __restrict__ c1lut,
                                             const float* __restrict__ cpref,
                                             const uint8_t* __restrict__ bits_in,
                                             const uint32_t* __restrict__ kLoA,
                                             const uint32_t* __restrict__ kHiA,
                                             int* __restrict__ out,
                                             uint8_t* __restrict__ bits_out,
                                             uint32_t* __restrict__ bandcnt,
                                             uint32_t* __restrict__ cntabove,
                                             uint2* __restrict__ bandpair) {
  #pragma clang fp contract(off)
  __shared__ uint32_t lbase, labove, gbase;
  if (threadIdx.x == 0) { lbase = 0; labove = 0; }
  __syncthreads();
  int row = blockIdx.x >> 6, slot = blockIdx.x & 63;
  int n0 = slot * HW_ + threadIdx.x * 8;
  uint32_t kLo = kLoA[row], kHi = kHiA[row];
  uint32_t blo = (kLo >= MARGIN) ? kLo - MARGIN : 0u;
  uint32_t bhi2 = kHi + MARGIN;
  uint32_t bhi = (bhi2 < kHi) ? 0xFFFFFFFFu : bhi2;   // saturate
  const float4* p = (const float4*)(U0 + (size_t)row * N_ + n0);
  float4 va = p[0], vb = p[1];
  float u[8] = {va.x, va.y, va.z, va.w, vb.x, vb.y, vb.z, vb.w};
  float c1 = c1lut[row * T_ + slot];
  float c2s = cpref[slot];
  float lc9 = cpref[64];
  uint8_t byte = TGT ? bits_in[(size_t)row * NB_ + (n0 >> 3)] : (uint8_t)0;
  int ov[8];
  uint32_t kk[8];
  uint32_t bandmask = 0, abovemask = 0;
  #pragma unroll
  for (int j = 0; j < 8; j++) {
    float c2 = TGT ? ((((byte >> j) & 1) != 0) ? lc9 : 0.0f) : c2s;
    float P = (fastln(u[j]) + c1) + c2;
    uint32_t k = fkey(P);
    kk[j] = k;
    if (k > bhi) { ov[j] = 1; abovemask |= (1u << j); }
    else { ov[j] = 0; if (k >= blo) bandmask |= (1u << j); }
  }
  int4 o0 = {ov[0], ov[1], ov[2], ov[3]};
  int4 o1 = {ov[4], ov[5], ov[6], ov[7]};
  int4* q = (int4*)(out + (size_t)row * N_ + n0);
  q[0] = o0; q[1] = o1;
  if (!TGT) bits_out[(size_t)row * NB_ + (n0 >> 3)] = (uint8_t)abovemask;
  int bp = __popc(bandmask), ap = __popc(abovemask);
  uint32_t mybase = 0;
  if (bp) mybase = atomicAdd(&lbase, (uint32_t)bp);
  if (ap) atomicAdd(&labove, (uint32_t)ap);
  __syncthreads();
  if (threadIdx.x == 0) {
    gbase = lbase ? atomicAdd(&bandcnt[row], lbase) : 0u;
    if (labove) atomicAdd(&cntabove[row], labove);
  }
  __syncthreads();
  if (bp) {
    uint32_t base = gbase + mybase;
    uint2* br = bandpair + (size_t)row * CAP;
    #pragma unroll
    for (int j = 0; j < 8; j++)
      if ((bandmask >> j) & 1u) {
        uint32_t pos = base + (uint32_t)__popc(bandmask & ((1u << j) - 1u));
        if (pos < CAP) { uint2 e; e.x = (uint32_t)(n0 + j); e.y = kk[j]; br[pos] = e; }
      }
  }
}

// ---------- E: streaming refine with parallel suffix-scan rank find ----------
template <bool TGT>
__global__ __launch_bounds__(1024) void resolveE(const float* __restrict__ U0,
                                                 const float* __restrict__ c1lut,
                                                 const float* __restrict__ cpref,
                                                 const uint8_t* __restrict__ bits_in,
                                                 const int* __restrict__ pK,
                                                 const uint32_t* __restrict__ kLoA,
                                                 const uint32_t* __restrict__ kHiA,
                                                 const uint32_t* __restrict__ bandcnt,
                                                 const uint32_t* __restrict__ cntabove,
                                                 const uint2* __restrict__ bandpair,
                                                 int* __restrict__ out,
                                                 uint8_t* __restrict__ bits_out) {
  #pragma clang fp contract(off)
  __shared__ uint32_t subh[NB2];     // 36 KB
  __shared__ uint32_t ss[1024];      // 4 KB
  __shared__ uint32_t wk[WCAP];      // 8 KB
  __shared__ uint32_t wi[WCAP];      // 8 KB
  __shared__ uint32_t s_sbin, s_A, s_nw;
  int row = blockIdx.x, tid = threadIdx.x;
  for (int i = tid; i < NB2; i += 1024) subh[i] = 0;
  if (tid == 0) s_nw = 0;
  __syncthreads();
  uint32_t cnt = bandcnt[row]; if (cnt > CAP) cnt = CAP;
  uint32_t K = (uint32_t)*pK;
  uint32_t R = K - cntabove[row];           // >=1, <=cnt by construction
  uint32_t kLo = kLoA[row], kHi = kHiA[row];
  uint32_t blo = (kLo >= MARGIN) ? kLo - MARGIN : 0u;
  uint32_t bhi2 = kHi + MARGIN;
  uint32_t bhi = (bhi2 < kHi) ? 0xFFFFFFFFu : bhi2;
  uint32_t range = bhi - blo;
  int wb = 6;
  while ((range >> wb) + 2u > (uint32_t)NB2) wb++;
  int NW = (int)(2048u >> wb); if (NW < 2) NW = 2;
  const uint2* bp = bandpair + (size_t)row * CAP;

  // pass 1: fast-key sub-histogram
  for (uint32_t i = tid; i < cnt; i += 1024) {
    uint32_t bin = (bp[i].y - blo) >> wb;
    if (bin >= (uint32_t)NB2) bin = NB2 - 1;
    atomicAdd(&subh[bin], 1u);
  }
  __syncthreads();
  // suffix scan over 1024 chunks of 9
  {
    uint32_t s = 0; int c0 = tid * 9;
    #pragma unroll
    for (int i = 0; i < 9; i++) s += subh[c0 + i];
    ss[tid] = s;
  }
  __syncthreads();
  for (int d = 1; d < 1024; d <<= 1) {
    uint32_t v = ss[tid] + ((tid + d < 1024) ? ss[tid + d] : 0u);
    __syncthreads();
    ss[tid] = v;
    __syncthreads();
  }
  // parallel find sbin for rank R
  {
    bool hit = (ss[tid] >= R) && (tid == 1023 || ss[tid + 1] < R);
    if (hit) {
      uint32_t run = (tid == 1023) ? 0u : ss[tid + 1];
      int b = tid * 9 + 8;
      for (; b > tid * 9; b--) {
        uint32_t nb = run + subh[b];
        if (nb >= R) break;
        run = nb;
      }
      s_sbin = (uint32_t)b;
    }
  }
  __syncthreads();
  int sbin = (int)s_sbin;
  if (tid == 0) {
    int bq = sbin + NW + 1;            // A = count of keys in bins >= bq
    uint32_t A = 0;
    if (bq < NB2) {
      int cq = bq / 9;
      A = (cq + 1 < 1024) ? ss[cq + 1] : 0u;
      for (int b = cq * 9 + 8; b >= bq; b--) A += subh[b];
    }
    s_A = A;
  }
  __syncthreads();
  uint32_t R2 = R - s_A;                    // to select from W window; >=1
  int* orow = out + (size_t)row * N_;

  // pass 2: classify band; definite-selects written, W collected
  for (uint32_t i = tid; i < cnt; i += 1024) {
    uint2 e = bp[i];
    uint32_t bin = (e.y - blo) >> wb;
    if (bin >= (uint32_t)NB2) bin = NB2 - 1;
    if ((int)bin > sbin + NW) {
      orow[e.x] = 1;
      if (!TGT) atomicOr((uint32_t*)(bits_out + (size_t)row * NB_) + (e.x >> 5), 1u << (e.x & 31));
    } else if ((int)bin >= sbin - NW) {
      uint32_t ppos = atomicAdd(&s_nw, 1u);
      if (ppos < WCAP) wi[ppos] = e.x;
    }
  }
  __syncthreads();
  uint32_t nw = s_nw; if (nw > WCAP) nw = WCAP;
  // pass 3a: exact keys for W
  const uint8_t* rb = bits_in + (size_t)row * NB_;
  const float* rowp = U0 + (size_t)row * N_;
  float lc9 = cpref[64];
  for (uint32_t i = tid; i < nw; i += 1024) {
    uint32_t idx = wi[i];
    uint32_t t = idx >> 11;
    float c2 = TGT ? ((((rb[idx >> 3] >> (idx & 7)) & 1) != 0) ? lc9 : 0.0f) : cpref[t];
    float P = (exactln(rowp[idx]) + c1lut[row * T_ + t]) + c2;
    wk[i] = fkey(P);
  }
  __syncthreads();
  // pass 3b: stable pairwise rank in W, select top R2
  for (uint32_t i = tid; i < nw; i += 1024) {
    uint32_t k = wk[i], id = wi[i], r = 0;
    for (uint32_t j = 0; j < nw; j++) {
      uint32_t kj = wk[j];
      r += (uint32_t)((kj > k) || (kj == k && wi[j] < id));
    }
    if (r < R2) {
      orow[id] = 1;
      if (!TGT) atomicOr((uint32_t*)(bits_out + (size_t)row * NB_) + (id >> 5), 1u << (id & 31));
    }
  }
}

// ---------- launch ----------
extern "C" void kernel_launch(void* const* d_in, const int* in_sizes, int n_in,
                              void* d_out, int out_size, void* d_ws, size_t ws_size,
                              hipStream_t stream) {
  const float* U0s = (const float*)d_in[0];
  const float* Uts = (const float*)d_in[1];
  const float* U0t = (const float*)d_in[2];
  const float* Utt = (const float*)d_in[3];
  const int* Ks = (const int*)d_in[4];
  const int* Kt = (const int*)d_in[5];
  int* out = (int*)d_out;
  char* ws = (char*)d_ws;

  // ws layout: bandpair 32 MiB | bits 2 MiB | small area (~35.7 MB total)
  uint2*    bandpair = (uint2*)ws;                         // 128*32768*8 = 33,554,432
  uint8_t*  bits     = (uint8_t*)(ws + 33554432);          // 2 MiB
  char*     sm       = ws + 35651584;
  uint32_t* bandcnt  = (uint32_t*)(sm + 0);
  uint32_t* cntabv   = (uint32_t*)(sm + 512);
  uint32_t* kLoA     = (uint32_t*)(sm + 1024);
  uint32_t* kHiA     = (uint32_t*)(sm + 1536);
  float*    c1src    = (float*)(sm + 2048);
  float*    c1tgt    = (float*)(sm + 2048 + 32768);
  float*    cpref    = (float*)(sm + 2048 + 65536);

  lut_kernel<<<B_, T_, 0, stream>>>(Uts, Utt, c1src, c1tgt, cpref);

  // ---- SRC mask -> out[0 .. B*N) ----
  sampleBand<false><<<B_, 1024, 0, stream>>>(U0s, c1src, cpref, nullptr, Ks,
                                             kLoA, kHiA, bandcnt, cntabv);
  maskD<false><<<FULLG, 256, 0, stream>>>(U0s, c1src, cpref, nullptr, kLoA, kHiA,
                                          out, bits, bandcnt, cntabv, bandpair);
  resolveE<false><<<B_, 1024, 0, stream>>>(U0s, c1src, cpref, nullptr, Ks, kLoA, kHiA,
                                           bandcnt, cntabv, bandpair, out, bits);

  // ---- TGT mask (conditioned on src bits) -> out[B*N .. 2*B*N) ----
  int* out2 = out + (size_t)B_ * N_;
  sampleBand<true><<<B_, 1024, 0, stream>>>(U0t, c1tgt, cpref, bits, Kt,
                                            kLoA, kHiA, bandcnt, cntabv);
  maskD<true><<<FULLG, 256, 0, stream>>>(U0t, c1tgt, cpref, bits, kLoA, kHiA,
                                         out2, nullptr, bandcnt, cntabv, bandpair);
  resolveE<true><<<B_, 1024, 0, stream>>>(U0t, c1tgt, cpref, bits, Kt, kLoA, kHiA,
                                          bandcnt, cntabv, bandpair, out2, nullptr);
}